// Round 6
// baseline (633.764 us; speedup 1.0000x reference)
//
#include <hip/hip_runtime.h>
#include <math.h>

#define D_DIM 2048
#define NE    64
#define NTOK  16384
#define TK    8
#define TOKB  16                 // tokens per block (shared by the 4 K-split waves)
#define KS    4                  // K-split: 4 waves per block, 512 d each
#define KD    (D_DIM / KS)       // 512
#define NQ    (KD / 4)           // 128 quads per wave slice
#define BT    256                // 4 waves

#define SROW  68                 // padded row for [tok][expert] LDS tiles
#define LDSF  (KS * TOKB * SROW) // 4352 floats = 17408 B

#define OUT_I_OFF (NTOK * TK)
#define OUT_S_OFF (2 * NTOK * TK)

// Barrier-free register GEMM. Wave = 16 tokens x 64 experts x 512-d K-slice.
// Lane (lt=lane>>3, le=lane&7): tokens {lt, 8+lt}, experts {j*8+le}, acc 2x8.
// x: per-lane float4 direct global (8 same-lt lanes coalesce; x read once total).
// w: per-lane float4 from L2 (512 KB resident; ~512 MB aggregate ~= 15 us at L2 BW).
// Both 1-step ping-pong prefetched; NO __syncthreads in the main loop -> waves
// fully independent, no vmcnt entanglement (in-order vmcnt retirement only ever
// waits on the wave's own 1-step-old prefetch). Epilogue: one small LDS
// reduction over the 4 K-slices + verified top-8, per 16-token block.
// __launch_bounds__(256,3): 2nd arg behaves as min-BLOCKS-per-CU (measured
// r1/r4/r5: cap = 512/(arg*waves_per_block/4)) -> VGPR cap ~170, no spill
// (r4 lesson: a too-low cap = scratch catastrophe), ~3 waves/SIMD.
__global__ __launch_bounds__(BT, 3) void gate_fused(const float* __restrict__ x,
                                                    const float* __restrict__ w,
                                                    const float* __restrict__ gb,
                                                    float* __restrict__ out) {
    __shared__ __align__(16) float part[LDSF];   // [ks][tok][SROW]

    float* scores = out + OUT_S_OFF;
    const int tid  = threadIdx.x;
    const int lane = tid & 63;
    const int ks   = tid >> 6;     // wave id = K-slice
    const int lt   = lane >> 3;    // token slot
    const int le   = lane & 7;     // expert slot
    const int tok0 = blockIdx.x * TOKB;

    // w rows: expert j*8+le, this wave's 512-d slice (le-divergent -> vector loads)
    const float4* wp[8];
#pragma unroll
    for (int j = 0; j < 8; ++j)
        wp[j] = (const float4*)w + (size_t)(j * 8 + le) * (D_DIM / 4) + ks * NQ;

    // x rows: tokens tok0+lt and tok0+8+lt, same d-slice
    const float4* xpA = (const float4*)x + (size_t)(tok0 + lt) * (D_DIM / 4) + ks * NQ;
    const float4* xpB = xpA + 8 * (D_DIM / 4);

    float acc0[8], acc1[8];
#pragma unroll
    for (int j = 0; j < 8; ++j) { acc0[j] = 0.f; acc1[j] = 0.f; }

    float4 wc[8], wn[8], xca, xcb, xna, xnb;
#pragma unroll
    for (int j = 0; j < 8; ++j) wc[j] = wp[j][0];
    xca = xpA[0];
    xcb = xpB[0];

    // one step = 4 d: FMA on resident (WC,xa,xb), prefetch quad nq into (WN,na,nb)
    auto step = [&](float4 (&WC)[8], float4 (&WN)[8],
                    float4& xa, float4& xb, float4& na, float4& nb, int nq) {
#pragma unroll
        for (int j = 0; j < 8; ++j) WN[j] = wp[j][nq];
        na = xpA[nq];
        nb = xpB[nq];
#pragma unroll
        for (int j = 0; j < 8; ++j) {
            acc0[j] = fmaf(xa.x, WC[j].x, acc0[j]);
            acc0[j] = fmaf(xa.y, WC[j].y, acc0[j]);
            acc0[j] = fmaf(xa.z, WC[j].z, acc0[j]);
            acc0[j] = fmaf(xa.w, WC[j].w, acc0[j]);
            acc1[j] = fmaf(xb.x, WC[j].x, acc1[j]);
            acc1[j] = fmaf(xb.y, WC[j].y, acc1[j]);
            acc1[j] = fmaf(xb.z, WC[j].z, acc1[j]);
            acc1[j] = fmaf(xb.w, WC[j].w, acc1[j]);
        }
    };

    for (int q = 0; q < NQ; q += 2) {
        step(wc, wn, xca, xcb, xna, xnb, (q + 1) & (NQ - 1));
        step(wn, wc, xna, xnb, xca, xcb, (q + 2) & (NQ - 1));
    }

    // ---- epilogue: partials -> LDS ----
    {
        float* pr = part + ks * (TOKB * SROW);
#pragma unroll
        for (int j = 0; j < 8; ++j) {
            pr[lt * SROW + j * 8 + le]       = acc0[j];
            pr[(8 + lt) * SROW + j * 8 + le] = acc1[j];
        }
    }
    __syncthreads();

    // reduce over ks + sigmoid + gb; store scores to global; final row into part[0]
    {
        const int t  = tid >> 4;       // token 0..15
        const int qe = tid & 15;       // expert quad 0..15
        float4 s = {0.f, 0.f, 0.f, 0.f};
#pragma unroll
        for (int k = 0; k < KS; ++k) {
            float4 a = *(const float4*)(part + k * (TOKB * SROW) + t * SROW + qe * 4);
            s.x += a.x; s.y += a.y; s.z += a.z; s.w += a.w;
        }
        float4 g = *(const float4*)(gb + qe * 4);
        float4 r;
        r.x = 1.f / (1.f + expf(-s.x)) + g.x;
        r.y = 1.f / (1.f + expf(-s.y)) + g.y;
        r.z = 1.f / (1.f + expf(-s.z)) + g.z;
        r.w = 1.f / (1.f + expf(-s.w)) + g.w;
        *(float4*)(scores + (size_t)(tok0 + t) * NE + qe * 4) = r;
        // in-place: only this thread reads part[0][t][qe*4..+3] afterwards-safe
        *(float4*)(part + t * SROW + qe * 4) = r;
    }
    __syncthreads();

    // ---- fused top-8 + normalize (wave 0: 4 lanes/token; ties -> lower index) ----
    if (tid < 64) {
        const int t  = tid >> 2;       // token 0..15
        const int q4 = tid & 3;
        float v[16];
        const float4* sp = (const float4*)(part + t * SROW + q4 * 16);
        float4 a = sp[0], b = sp[1], c = sp[2], d = sp[3];
        v[0] = a.x;  v[1] = a.y;  v[2] = a.z;  v[3] = a.w;
        v[4] = b.x;  v[5] = b.y;  v[6] = b.z;  v[7] = b.w;
        v[8] = c.x;  v[9] = c.y;  v[10] = c.z; v[11] = c.w;
        v[12] = d.x; v[13] = d.y; v[14] = d.z; v[15] = d.w;

        float kv[TK]; int ki[TK];
#pragma unroll
        for (int k = 0; k < TK; ++k) {
            float bv = v[0]; int bi = q4 * 16;
#pragma unroll
            for (int j = 1; j < 16; ++j) {
                bool gt = v[j] > bv;
                bv = gt ? v[j] : bv;
                bi = gt ? (q4 * 16 + j) : bi;
            }
#pragma unroll
            for (int off = 1; off < 4; off <<= 1) {
                float ov = __shfl_xor(bv, off);
                int   oi = __shfl_xor(bi, off);
                bool take = (ov > bv) || (ov == bv && oi < bi);
                bv = take ? ov : bv;
                bi = take ? oi : bi;
            }
            int lj = bi - q4 * 16;
#pragma unroll
            for (int j = 0; j < 16; ++j) v[j] = (j == lj) ? -3e38f : v[j];
            kv[k] = bv; ki[k] = bi;
        }

        if (q4 == 0) {
            float s = 0.f;
#pragma unroll
            for (int k = 0; k < TK; ++k) s += kv[k];
            float inv = 1.f / s;
            float* ow = out + (size_t)(tok0 + t) * TK;
            float* oi = out + OUT_I_OFF + (size_t)(tok0 + t) * TK;
#pragma unroll
            for (int k = 0; k < TK; ++k) {
                ow[k] = kv[k] * inv;
                oi[k] = (float)ki[k];
            }
        }
    }
}

extern "C" void kernel_launch(void* const* d_in, const int* in_sizes, int n_in,
                              void* d_out, int out_size, void* d_ws, size_t ws_size,
                              hipStream_t stream) {
    const float* x  = (const float*)d_in[0];
    const float* w  = (const float*)d_in[1];
    const float* gb = (const float*)d_in[2];
    float* out = (float*)d_out;
    (void)in_sizes; (void)n_in; (void)out_size; (void)d_ws; (void)ws_size;

    gate_fused<<<dim3(NTOK / TOKB), dim3(BT), 0, stream>>>(x, w, gb, out);
}

// Round 7
// 257.196 us; speedup vs baseline: 2.4641x; 2.4641x over previous
//
#include <hip/hip_runtime.h>
#include <math.h>

#define D_DIM 2048
#define NE    64
#define NTOK  16384
#define TK    8
#define TOKB  64                 // tokens per block (all 8 waves share them)
#define BT    512                // 8 waves
#define CHD   64                 // d per chunk (block-wide); wave ks owns 8 of them
#define NCHK  (D_DIM / CHD)      // 32 chunks
#define WCH   4096               // floats per w staging buffer: 64 e x 64 d

#define RROW  68                 // padded row (64 + 4) for reduction/topk tiles
#define SLICE (TOKB * RROW)      // 4352 floats
#define POOLF (4 * SLICE)        // 17408 floats = 69632 B  (>= 2*WCH staging)

#define OUT_I_OFF (NTOK * TK)
#define OUT_S_OFF (2 * NTOK * TK)

#define GLOBAL_AS __attribute__((address_space(1)))
#define LDS_AS    __attribute__((address_space(3)))

static __device__ __forceinline__ void async_copy16(const float* g, float* l) {
    // offset immediate ALWAYS 0 (r2 lesson).
    __builtin_amdgcn_global_load_lds((const GLOBAL_AS void*)g, (LDS_AS void*)l, 16, 0, 0);
}

// Block = 64 tokens x 64 experts x full K. 8 waves split each 64-d chunk
// (wave ks handles d in [c*64 + ks*8, +8)), all sharing ONE 16 KB w-chunk in LDS.
// w: global_load_lds staged, XOR-swizzled on the GLOBAL side (slot qp of expert e
// holds logical quad qp ^ (e&7); read addr e*64 + ((qL^le)<<2) -> 8 distinct
// bank-quads, conflict-free broadcast). x: per-lane float4 direct from L3
// (8 distinct 16B lines/instr; x is L3-resident across dispatches - r5/r6 FETCH).
// Lane (lt=lane>>3, le=lane&7): 8 tokens x 8 experts acc. w-operand waits are
// lgkmcnt(ds_read) - the path the compiler pipelines well; staging DMA issued a
// full chunk ahead of its barrier so vmcnt(0)@barrier is pre-drained (r5 lesson);
// x VMEM stalls decorrelated across waves (no mid-chunk syncs, r6 lesson).
// Epilogue: in-block split-K reduction + sigmoid+gb + verified top-8.
__global__ __launch_bounds__(BT, 1) void gate_fused(const float* __restrict__ x,
                                                    const float* __restrict__ w,
                                                    const float* __restrict__ gb,
                                                    float* __restrict__ out) {
    __shared__ __align__(16) float pool[POOLF];

    float* scores = out + OUT_S_OFF;
    const int tid  = threadIdx.x;
    const int lane = tid & 63;
    const int ks   = tid >> 6;     // wave id: which 8-d sub-slice of each chunk
    const int lt   = lane >> 3;    // token slot 0..7
    const int le   = lane & 7;     // expert slot 0..7
    const int tok0 = blockIdx.x * TOKB;

    // ---- staging map (thread covers quads m = tid and tid+512 of the 1024-quad chunk)
    // m -> (e = m>>4, qp = m&15); slot qp holds logical quad qp ^ (e&7).
    // (e+32)&7 == e&7, so the second quad is src0 + 32 rows.
    const int e0  = tid >> 4;
    const int qp0 = tid & 15;
    const float* src0 = w + (size_t)e0 * D_DIM + ((qp0 ^ (e0 & 7)) << 2);

    auto stage = [&](int c, int buf) {
        float* d = pool + buf * WCH + tid * 4;
        async_copy16(src0 + c * CHD, d);
        async_copy16(src0 + 32 * D_DIM + c * CHD, d + 2048);
    };

    // ---- x row pointers: tokens i*8+lt (8 lanes with same lt share the address)
    const float4* xq[8];
#pragma unroll
    for (int i = 0; i < 8; ++i)
        xq[i] = (const float4*)x + (size_t)(tok0 + i * 8 + lt) * (D_DIM / 4);

    float acc[8][8];
#pragma unroll
    for (int i = 0; i < 8; ++i)
#pragma unroll
        for (int j = 0; j < 8; ++j) acc[i][j] = 0.f;

    stage(0, 0);

    for (int c = 0; c < NCHK; ++c) {
        __syncthreads();                         // chunk-c w staged (issued 1 chunk ago)
        if (c + 1 < NCHK) stage(c + 1, (c + 1) & 1);
        const float* wb = pool + (c & 1) * WCH;
#pragma unroll
        for (int qq = 0; qq < 2; ++qq) {
            const int qL = ks * 2 + qq;          // this wave's 4-d window in the chunk
            float4 xi[8];
#pragma unroll
            for (int i = 0; i < 8; ++i) xi[i] = xq[i][c * 16 + qL];
            float4 wj[8];
#pragma unroll
            for (int j = 0; j < 8; ++j)
                wj[j] = *(const float4*)(wb + (j * 8 + le) * 64 + ((qL ^ le) << 2));
#pragma unroll
            for (int i = 0; i < 8; ++i) {
#pragma unroll
                for (int j = 0; j < 8; ++j) {
                    acc[i][j] = fmaf(xi[i].x, wj[j].x, acc[i][j]);
                    acc[i][j] = fmaf(xi[i].y, wj[j].y, acc[i][j]);
                    acc[i][j] = fmaf(xi[i].z, wj[j].z, acc[i][j]);
                    acc[i][j] = fmaf(xi[i].w, wj[j].w, acc[i][j]);
                }
            }
        }
    }

    // ---- split-K reduction over the 8 waves (pool reused; padded rows) ----
    __syncthreads();
    if (ks >= 4) {                 // phase0: waves 4..7 store into slices 0..3
        float* pr = pool + (ks - 4) * SLICE;
#pragma unroll
        for (int i = 0; i < 8; ++i)
#pragma unroll
            for (int j = 0; j < 8; ++j)
                pr[(i * 8 + lt) * RROW + j * 8 + le] = acc[i][j];
    }
    __syncthreads();
    if (ks < 4) {                  // phase1: waves 0..3 add into their slice
        float* pr = pool + ks * SLICE;
#pragma unroll
        for (int i = 0; i < 8; ++i)
#pragma unroll
            for (int j = 0; j < 8; ++j)
                pr[(i * 8 + lt) * RROW + j * 8 + le] += acc[i][j];
    }
    __syncthreads();
    // phase2: sum 4 slices, sigmoid+gb, write scores, stash final row in slice 0.
    // Cell ownership: thread k-round v = k*512+tid covers t<32 then t>=32 - the
    // slice-0 in-place writes never alias another thread's reads.
#pragma unroll
    for (int k = 0; k < 2; ++k) {
        const int v  = k * 512 + tid;
        const int t  = v >> 4;
        const int e4 = v & 15;
        float4 s = {0.f, 0.f, 0.f, 0.f};
#pragma unroll
        for (int sl = 0; sl < 4; ++sl) {
            float4 a = *(const float4*)(pool + sl * SLICE + t * RROW + e4 * 4);
            s.x += a.x; s.y += a.y; s.z += a.z; s.w += a.w;
        }
        float4 g = *(const float4*)(gb + e4 * 4);
        float4 r;
        r.x = 1.f / (1.f + expf(-s.x)) + g.x;
        r.y = 1.f / (1.f + expf(-s.y)) + g.y;
        r.z = 1.f / (1.f + expf(-s.z)) + g.z;
        r.w = 1.f / (1.f + expf(-s.w)) + g.w;
        *(float4*)(scores + (size_t)(tok0 + t) * NE + e4 * 4) = r;
        *(float4*)(pool + t * RROW + e4 * 4) = r;
    }
    __syncthreads();

    // ---- fused top-8 + normalize (4 lanes per token; ties -> lower index) ----
    if (tid < 256) {
        const int t  = tid >> 2;       // token 0..63
        const int q4 = tid & 3;
        float v[16];
        const float4* sp = (const float4*)(pool + t * RROW + q4 * 16);
        float4 a = sp[0], b = sp[1], c = sp[2], d = sp[3];
        v[0] = a.x;  v[1] = a.y;  v[2] = a.z;  v[3] = a.w;
        v[4] = b.x;  v[5] = b.y;  v[6] = b.z;  v[7] = b.w;
        v[8] = c.x;  v[9] = c.y;  v[10] = c.z; v[11] = c.w;
        v[12] = d.x; v[13] = d.y; v[14] = d.z; v[15] = d.w;

        float kv[TK]; int ki[TK];
#pragma unroll
        for (int k = 0; k < TK; ++k) {
            float bv = v[0]; int bi = q4 * 16;
#pragma unroll
            for (int j = 1; j < 16; ++j) {
                bool gt = v[j] > bv;
                bv = gt ? v[j] : bv;
                bi = gt ? (q4 * 16 + j) : bi;
            }
#pragma unroll
            for (int off = 1; off < 4; off <<= 1) {
                float ov = __shfl_xor(bv, off);
                int   oi = __shfl_xor(bi, off);
                bool take = (ov > bv) || (ov == bv && oi < bi);
                bv = take ? ov : bv;
                bi = take ? oi : bi;
            }
            int lj = bi - q4 * 16;
#pragma unroll
            for (int j = 0; j < 16; ++j) v[j] = (j == lj) ? -3e38f : v[j];
            kv[k] = bv; ki[k] = bi;
        }

        if (q4 == 0) {
            float s = 0.f;
#pragma unroll
            for (int k = 0; k < TK; ++k) s += kv[k];
            float inv = 1.f / s;
            float* ow = out + (size_t)(tok0 + t) * TK;
            float* oi = out + OUT_I_OFF + (size_t)(tok0 + t) * TK;
#pragma unroll
            for (int k = 0; k < TK; ++k) {
                ow[k] = kv[k] * inv;
                oi[k] = (float)ki[k];
            }
        }
    }
}

extern "C" void kernel_launch(void* const* d_in, const int* in_sizes, int n_in,
                              void* d_out, int out_size, void* d_ws, size_t ws_size,
                              hipStream_t stream) {
    const float* x  = (const float*)d_in[0];
    const float* w  = (const float*)d_in[1];
    const float* gb = (const float*)d_in[2];
    float* out = (float*)d_out;
    (void)in_sizes; (void)n_in; (void)out_size; (void)d_ws; (void)ws_size;

    gate_fused<<<dim3(NTOK / TOKB), dim3(BT), 0, stream>>>(x, w, gb, out);
}